// Round 3
// baseline (271.003 us; speedup 1.0000x reference)
//
#include <hip/hip_runtime.h>
#include <hip/hip_bf16.h>
#include <cstdint>

// Problem constants (B=4, S=2048, D2=1024, DV=64, d_k=64)
#define S_LEN 2048
#define D2_   1024
#define DV_   64
#define NB_   4

typedef __bf16 bf16x8 __attribute__((ext_vector_type(8)));
typedef float  f32x4  __attribute__((ext_vector_type(4)));

// fp32 -> bf16 round-to-nearest-even
__device__ __forceinline__ unsigned short f2bf(float f) {
  union { float f; unsigned int u; } v; v.f = f;
  unsigned int r = v.u + 0x7fffu + ((v.u >> 16) & 1u);
  return (unsigned short)(r >> 16);
}

// async global->LDS, 16B per lane (global_load_lds_dwordx4)
__device__ __forceinline__ void async16(const unsigned short* g, unsigned short* l) {
  __builtin_amdgcn_global_load_lds(
      (__attribute__((address_space(1))) void*)g,
      (__attribute__((address_space(3))) void*)l,
      16, 0, 0);
}

// ---------------------------------------------------------------------------
// Kernel 1 (fused prep): per row r:
//   qn[r,:] = bf16( LN(q[r,:]) * 0.125 )      (1/sqrt(64) folded in)
//   kb[r,:] = bf16( k[r,:] )
//   blocks 0..3:  w2[d] = fc_w[d,:] . V       (rank-1 collapse of @fc_w.T)
//   blocks 0..31: zero rowsum[] (d_ws is poisoned 0xAA before every launch)
// ---------------------------------------------------------------------------
__global__ void __launch_bounds__(256) prep_kernel(
    const float* __restrict__ q, const float* __restrict__ k,
    const float* __restrict__ gam, const float* __restrict__ bet,
    const float* __restrict__ V, const float* __restrict__ fw,
    unsigned short* __restrict__ qn, unsigned short* __restrict__ kb,
    float* __restrict__ w2, float* __restrict__ rowsum) {
  const int row = blockIdx.x;
  const int t = threadIdx.x;

  if (row < 32) rowsum[row * 256 + t] = 0.0f;   // 8192 floats total

  // ---- LN(q) ----
  const float4 x = ((const float4*)(q + (size_t)row * D2_))[t];
  float s  = x.x + x.y + x.z + x.w;
  float ss = x.x * x.x + x.y * x.y + x.z * x.z + x.w * x.w;
  #pragma unroll
  for (int o = 32; o > 0; o >>= 1) { s += __shfl_down(s, o); ss += __shfl_down(ss, o); }
  __shared__ float red[8];
  if ((t & 63) == 0) { red[t >> 6] = s; red[(t >> 6) + 4] = ss; }
  __syncthreads();
  const float tot  = red[0] + red[1] + red[2] + red[3];
  const float tots = red[4] + red[5] + red[6] + red[7];
  const float mu  = tot * (1.0f / D2_);
  const float var = tots * (1.0f / D2_) - mu * mu;
  const float rs  = rsqrtf(var + 1e-6f) * 0.125f;
  const float4 gv = ((const float4*)gam)[t];
  const float4 bv = ((const float4*)bet)[t];
  ushort4 o4;
  o4.x = f2bf((x.x - mu) * rs * gv.x + 0.125f * bv.x);
  o4.y = f2bf((x.y - mu) * rs * gv.y + 0.125f * bv.y);
  o4.z = f2bf((x.z - mu) * rs * gv.z + 0.125f * bv.z);
  o4.w = f2bf((x.w - mu) * rs * gv.w + 0.125f * bv.w);
  ((ushort4*)(qn + (size_t)row * D2_))[t] = o4;

  // ---- cast k row ----
  const float4 kx = ((const float4*)(k + (size_t)row * D2_))[t];
  ushort4 k4;
  k4.x = f2bf(kx.x); k4.y = f2bf(kx.y); k4.z = f2bf(kx.z); k4.w = f2bf(kx.w);
  ((ushort4*)(kb + (size_t)row * D2_))[t] = k4;

  // ---- w2 (blocks 0..3) ----
  if (row < 4) {
    const int d = row * 256 + t;
    const float4* r  = (const float4*)(fw + (size_t)d * DV_);
    const float4* vv = (const float4*)V;
    float acc = 0.f;
    #pragma unroll
    for (int j = 0; j < 16; ++j) {
      const float4 a = r[j], b = vv[j];
      acc += a.x * b.x + a.y * b.y + a.z * b.z + a.w * b.w;
    }
    w2[d] = acc;
  }
}

// ---------------------------------------------------------------------------
// Kernel 2: attn = masked( qn @ kb^T );  rowsum += per-row sums.
// R9: same proven 128B-stride XOR swizzle (R5/R6: 0 bank conflicts), but the
// serial {DMA -> drain -> compute} K-loop is replaced by a double-buffered
// 2-phase pipeline (BK 128 -> 64, 2 bufs, SAME 64 KiB LDS / 2 blocks/CU):
//   prologue: stage tile0 -> buf0; barrier
//   iter:     stage tile t+1 -> buf^1 ; compute buf ; barrier  (one/tile)
// The vmcnt(0)+barrier drain now lands AFTER a full compute phase instead of
// immediately after issue -> DMA latency hidden (old kernel: MfmaUtil 19%,
// HBM 32%, VALU 11% = nothing saturated = latency/barrier-bound).
// Layout per buffer (16 KiB per matrix): row r (128 rows, 128B stride),
// granule s (8 bf16) at (s ^ (r&7))*16B.  DMA op rh in {0,1}: thread t covers
// row rh*64+(t>>3), dest = base + rh*8KiB + t*16B; global granule (t&7)^(row&7).
// MFMA operands swapped (kb first) so reg quad = 4 consecutive attn cols.
// Mask slice prefetched to registers before the K-loop.
// Extras: XCD-chunked block swizzle (1024 wgs % 8 == 0, bijective) for
// A-panel L2 reuse; nontemporal attn stores (write-once 64 MB stream).
// ---------------------------------------------------------------------------
__global__ void __launch_bounds__(512, 4) attn_gemm_kernel(
    const unsigned short* __restrict__ qn,   // [B*S, D2] bf16
    const unsigned short* __restrict__ kb,   // [B*S, D2] bf16
    const int* __restrict__ mask,            // [B, S, S] int32
    float* __restrict__ attn,                // [B, S, S] f32
    float* __restrict__ rowsum) {            // [B*S] f32 (pre-zeroed)
  __shared__ __align__(16) unsigned short Asm_[2 * 8192];   // 2 bufs x 16 KiB
  __shared__ __align__(16) unsigned short Bsm_[2 * 8192];

  const int t = threadIdx.x;

  // XCD-chunked swizzle: XCD c owns contiguous work ids [c*128, (c+1)*128)
  // = 8 m-panels x all 16 n-panels (A panel reused 16x inside one L2).
  const int orig = blockIdx.x + 16 * (blockIdx.y + 16 * blockIdx.z);
  const int swz  = (orig & 7) * 128 + (orig >> 3);
  const int bn = (swz & 15) * 128;
  const int bm = ((swz >> 4) & 15) * 128;
  const int bt = swz >> 8;

  // staging base: thread t -> row (t>>3), permuted granule (t&7)^(row&7)
  const int srow_ = t >> 3;
  const int pg_   = (t & 7) ^ (srow_ & 7);
  const unsigned short* gA = qn + ((size_t)bt * S_LEN + bm + srow_) * D2_ + pg_ * 8;
  const unsigned short* gB = kb + ((size_t)bt * S_LEN + bn + srow_) * D2_ + pg_ * 8;
  unsigned short* lA = Asm_ + t * 8;
  unsigned short* lB = Bsm_ + t * 8;

  const int lane = t & 63;
  const int w  = t >> 6;
  const int wm = (w >> 2) * 64;   // wave m offset (0/64)
  const int wn = (w & 3) * 32;    // wave n offset (0/32/64/96)
  const int lr = lane & 15;
  const int lg = lane >> 4;

  // stage one 64-wide K-tile into buffer at LDS short-offset `buf` (0 or 8192)
  #define STAGE64(buf, koff) do {                                   \
      async16(gA + (koff),            lA + (buf));                  \
      async16(gA + (koff) + 64 * D2_, lA + (buf) + 4096);           \
      async16(gB + (koff),            lB + (buf));                  \
      async16(gB + (koff) + 64 * D2_, lB + (buf) + 4096);           \
    } while (0)

  // prologue: tile 0 -> buf0, then mask prefetch overlaps the DMA
  STAGE64(0, 0);

  const int m_base = bm + wm + lr;
  const size_t rb0 = ((size_t)bt * S_LEN) * S_LEN;
  int4 mk[4][2];
  #pragma unroll
  for (int fm = 0; fm < 4; ++fm)
    #pragma unroll
    for (int fn = 0; fn < 2; ++fn)
      mk[fm][fn] = *(const int4*)(mask + rb0 + (size_t)(m_base + fm * 16) * S_LEN
                                  + bn + wn + fn * 16 + lg * 4);

  f32x4 acc[4][2] = {};           // [fm][fn]

  // compute one staged 64-K tile from LDS short-offset pl (0 or 8192)
  auto compute = [&](int pl) {
    #pragma unroll
    for (int ks = 0; ks < 2; ++ks) {
      // K-chunk ks needs granule ks*4+lg: slot ((ks*4+lg) ^ (row&7)), row&7==lr&7
      const int sl = ((ks << 2) + lg) ^ (lr & 7);
      bf16x8 af[4], bfv[2];
      #pragma unroll
      for (int f = 0; f < 4; ++f)
        af[f]  = *(const bf16x8*)(Asm_ + pl + (wm + f * 16 + lr) * 64 + sl * 8);
      #pragma unroll
      for (int f = 0; f < 2; ++f)
        bfv[f] = *(const bf16x8*)(Bsm_ + pl + (wn + f * 16 + lr) * 64 + sl * 8);
      #pragma unroll
      for (int fm = 0; fm < 4; ++fm)
        #pragma unroll
        for (int fn = 0; fn < 2; ++fn)
          acc[fm][fn] = __builtin_amdgcn_mfma_f32_16x16x32_bf16(
              bfv[fn], af[fm], acc[fm][fn], 0, 0, 0);   // swapped order
    }
  };

  __syncthreads();   // tile 0 staged (drains vmcnt(0))

  // 16 K-tiles total; buf0 = even tiles, buf1 = odd tiles.
  // Each barrier: (a) proves next tile's DMA (issued a full compute ago) is
  // done, (b) proves all reads of the buffer about to be overwritten are done.
  #pragma unroll 1
  for (int kt = 0; kt < 14; kt += 2) {
    STAGE64(8192, (kt + 1) * 64);   // tile kt+1 -> buf1
    compute(0);                     // tile kt from buf0
    __syncthreads();
    STAGE64(0, (kt + 2) * 64);      // tile kt+2 -> buf0
    compute(8192);                  // tile kt+1 from buf1
    __syncthreads();
  }
  // tail: kt = 14
  STAGE64(8192, 15 * 64);
  compute(0);                       // tile 14
  __syncthreads();
  compute(8192);                    // tile 15 (no further staging/barrier)

  // epilogue: pure stores (mask already in registers) + rowsum reduce.
  #pragma unroll
  for (int fm = 0; fm < 4; ++fm) {
    const int m = m_base + fm * 16;
    const size_t rowbase = rb0 + (size_t)m * S_LEN;
    float s = 0.f;
    #pragma unroll
    for (int fn = 0; fn < 2; ++fn) {
      const int n0 = bn + wn + fn * 16 + lg * 4;
      f32x4 v;
      v[0] = mk[fm][fn].x ? 0.0f : acc[fm][fn][0];
      v[1] = mk[fm][fn].y ? 0.0f : acc[fm][fn][1];
      v[2] = mk[fm][fn].z ? 0.0f : acc[fm][fn][2];
      v[3] = mk[fm][fn].w ? 0.0f : acc[fm][fn][3];
      __builtin_nontemporal_store(v, (f32x4*)(attn + rowbase + n0));
      s += v[0] + v[1] + v[2] + v[3];
    }
    // reduce across the 4 lg groups sharing this row
    s += __shfl_xor(s, 16);
    s += __shfl_xor(s, 32);
    if (lane < 16) atomicAdd(rowsum + (size_t)bt * S_LEN + m, s);
  }
  #undef STAGE64
}

// ---------------------------------------------------------------------------
// Kernel 3: out[row,:] = rowsum[row] * w2[:] + fc_b[:] + q[row,:]
// (never touches attn).  Overwrites the out-region that held qn/kb; reads
// nothing from it — safe under stream ordering.
// ---------------------------------------------------------------------------
__global__ void __launch_bounds__(256) out_kernel(
    const float* __restrict__ rowsum, const float* __restrict__ q,
    const float* __restrict__ w2, const float* __restrict__ fcb,
    float* __restrict__ out) {
  const int row = blockIdx.x;
  const int t = threadIdx.x;
  const float rs = rowsum[row];
  const float4 wv = ((const float4*)w2)[t];
  const float4 bv = ((const float4*)fcb)[t];
  const float4 qv = ((const float4*)(q + (size_t)row * D2_))[t];
  float4 o4;
  o4.x = rs * wv.x + bv.x + qv.x;
  o4.y = rs * wv.y + bv.y + qv.y;
  o4.z = rs * wv.z + bv.z + qv.z;
  o4.w = rs * wv.w + bv.w + qv.w;
  ((float4*)(out + (size_t)row * D2_))[t] = o4;
}

// ---------------------------------------------------------------------------
extern "C" void kernel_launch(void* const* d_in, const int* in_sizes, int n_in,
                              void* d_out, int out_size, void* d_ws, size_t ws_size,
                              hipStream_t stream) {
  (void)in_sizes; (void)n_in; (void)out_size; (void)ws_size;
  const float* q    = (const float*)d_in[0];
  const float* k    = (const float*)d_in[1];
  /* d_in[2] == v: provably unused by the reference computation */
  const int*   mask = (const int*)d_in[3];
  const float* V    = (const float*)d_in[4];
  const float* fw   = (const float*)d_in[5];
  const float* fcb  = (const float*)d_in[6];
  const float* lg   = (const float*)d_in[7];
  const float* lb   = (const float*)d_in[8];

  float* out  = (float*)d_out;                          // [B,S,D2]  32 MiB
  float* attn = out + (size_t)NB_ * S_LEN * D2_;        // [B,S,S]   64 MiB

  // qn/kb live INSIDE the out-region (exactly 32 MiB), dead until out_kernel
  // overwrites it last.  d_ws: w2 (4 KiB) + rowsum (32 KiB).
  unsigned short* qn = (unsigned short*)out;                     // 16 MiB
  unsigned short* kb = qn + (size_t)NB_ * S_LEN * D2_;           // 16 MiB
  float* w2     = (float*)d_ws;                                  // 1024 f
  float* rowsum = w2 + D2_;                                      // 8192 f

  prep_kernel<<<NB_ * S_LEN, 256, 0, stream>>>(q, k, lg, lb, V, fw, qn, kb, w2, rowsum);
  attn_gemm_kernel<<<dim3(S_LEN / 128, S_LEN / 128, NB_), 512, 0, stream>>>(qn, kb, mask, attn, rowsum);
  out_kernel<<<NB_ * S_LEN, 256, 0, stream>>>(rowsum, q, w2, fcb, out);
}

// Round 4
// 269.829 us; speedup vs baseline: 1.0044x; 1.0044x over previous
//
#include <hip/hip_runtime.h>
#include <hip/hip_bf16.h>
#include <cstdint>

// Problem constants (B=4, S=2048, D2=1024, DV=64, d_k=64)
#define S_LEN 2048
#define D2_   1024
#define DV_   64
#define NB_   4

typedef __bf16 bf16x8 __attribute__((ext_vector_type(8)));
typedef float  f32x4  __attribute__((ext_vector_type(4)));
typedef int    i32x4  __attribute__((ext_vector_type(4)));

// fp32 -> bf16 round-to-nearest-even
__device__ __forceinline__ unsigned short f2bf(float f) {
  union { float f; unsigned int u; } v; v.f = f;
  unsigned int r = v.u + 0x7fffu + ((v.u >> 16) & 1u);
  return (unsigned short)(r >> 16);
}

// async global->LDS, 16B per lane (global_load_lds_dwordx4)
__device__ __forceinline__ void async16(const unsigned short* g, unsigned short* l) {
  __builtin_amdgcn_global_load_lds(
      (__attribute__((address_space(1))) void*)g,
      (__attribute__((address_space(3))) void*)l,
      16, 0, 0);
}

// ---------------------------------------------------------------------------
// Kernel 1 (fused prep): per row r:
//   qn[r,:] = bf16( LN(q[r,:]) * 0.125 )      (1/sqrt(64) folded in)
//   kb[r,:] = bf16( k[r,:] )
//   blocks 0..3:  w2[d] = fc_w[d,:] . V       (rank-1 collapse of @fc_w.T)
//   blocks 0..31: zero rowsum[] (d_ws is poisoned 0xAA before every launch)
// ---------------------------------------------------------------------------
__global__ void __launch_bounds__(256) prep_kernel(
    const float* __restrict__ q, const float* __restrict__ k,
    const float* __restrict__ gam, const float* __restrict__ bet,
    const float* __restrict__ V, const float* __restrict__ fw,
    unsigned short* __restrict__ qn, unsigned short* __restrict__ kb,
    float* __restrict__ w2, float* __restrict__ rowsum) {
  const int row = blockIdx.x;
  const int t = threadIdx.x;

  if (row < 32) rowsum[row * 256 + t] = 0.0f;   // 8192 floats total

  // ---- LN(q) ----
  const float4 x = ((const float4*)(q + (size_t)row * D2_))[t];
  float s  = x.x + x.y + x.z + x.w;
  float ss = x.x * x.x + x.y * x.y + x.z * x.z + x.w * x.w;
  #pragma unroll
  for (int o = 32; o > 0; o >>= 1) { s += __shfl_down(s, o); ss += __shfl_down(ss, o); }
  __shared__ float red[8];
  if ((t & 63) == 0) { red[t >> 6] = s; red[(t >> 6) + 4] = ss; }
  __syncthreads();
  const float tot  = red[0] + red[1] + red[2] + red[3];
  const float tots = red[4] + red[5] + red[6] + red[7];
  const float mu  = tot * (1.0f / D2_);
  const float var = tots * (1.0f / D2_) - mu * mu;
  const float rs  = rsqrtf(var + 1e-6f) * 0.125f;
  const float4 gv = ((const float4*)gam)[t];
  const float4 bv = ((const float4*)bet)[t];
  ushort4 o4;
  o4.x = f2bf((x.x - mu) * rs * gv.x + 0.125f * bv.x);
  o4.y = f2bf((x.y - mu) * rs * gv.y + 0.125f * bv.y);
  o4.z = f2bf((x.z - mu) * rs * gv.z + 0.125f * bv.z);
  o4.w = f2bf((x.w - mu) * rs * gv.w + 0.125f * bv.w);
  ((ushort4*)(qn + (size_t)row * D2_))[t] = o4;

  // ---- cast k row ----
  const float4 kx = ((const float4*)(k + (size_t)row * D2_))[t];
  ushort4 k4;
  k4.x = f2bf(kx.x); k4.y = f2bf(kx.y); k4.z = f2bf(kx.z); k4.w = f2bf(kx.w);
  ((ushort4*)(kb + (size_t)row * D2_))[t] = k4;

  // ---- w2 (blocks 0..3) ----
  if (row < 4) {
    const int d = row * 256 + t;
    const float4* r  = (const float4*)(fw + (size_t)d * DV_);
    const float4* vv = (const float4*)V;
    float acc = 0.f;
    #pragma unroll
    for (int j = 0; j < 16; ++j) {
      const float4 a = r[j], b = vv[j];
      acc += a.x * b.x + a.y * b.y + a.z * b.z + a.w * b.w;
    }
    w2[d] = acc;
  }
}

// ---------------------------------------------------------------------------
// Kernel 2: attn = masked( qn @ kb^T );  rowsum += per-row sums.
// R10: occupancy play.  R9 post-mortem: explicit dbuf at 2 blocks/CU was
// NEUTRAL (69.5->71.7) -> kernel is not DMA-latency-bound; implicit
// cross-block overlap already covered the drains (m114/m99/m100).  The
// limiter is TLP (Occupancy 36%).  So: SINGLE 32 KiB buffer (BK=64),
// __launch_bounds__(512,8) -> 4 blocks/CU = 32 waves/CU (100% cap), serial
// 2-barrier loop per K-tile; stalls filled by 3 sibling blocks (m97 recipe).
// Mask moved to the epilogue as NONTEMPORAL loads (frees the 32-VGPR int4
// prefetch array so 8 waves/SIMD fits; nt keeps the 64 MB one-shot mask
// stream from evicting qn/kb panels).  attn stores back to plain float4
// (R9: nt-store cost +5 MB HBM write).  XCD-chunked swizzle kept (proven:
// FETCH 106.7 -> 75.3 MB).  LDS layout per matrix (16 KiB): row r (128 rows,
// 128B stride), granule s at (s ^ (r&7))*16B; DMA covers row-half rh via
// thread t -> row rh*64+(t>>3), dest t*16B + rh*8KiB, global granule
// (t&7)^(row&7).  MFMA operands swapped (kb first) so reg quad = 4
// consecutive attn cols.
// ---------------------------------------------------------------------------
__global__ void __launch_bounds__(512, 8) attn_gemm_kernel(
    const unsigned short* __restrict__ qn,   // [B*S, D2] bf16
    const unsigned short* __restrict__ kb,   // [B*S, D2] bf16
    const int* __restrict__ mask,            // [B, S, S] int32
    float* __restrict__ attn,                // [B, S, S] f32
    float* __restrict__ rowsum) {            // [B*S] f32 (pre-zeroed)
  __shared__ __align__(16) unsigned short Asm_[8192];   // 16 KiB (single buf)
  __shared__ __align__(16) unsigned short Bsm_[8192];   // 16 KiB

  const int t = threadIdx.x;

  // XCD-chunked swizzle: XCD c owns contiguous work ids [c*128, (c+1)*128)
  // = 8 m-panels x all 16 n-panels (A panel reused 16x inside one L2).
  const int orig = blockIdx.x + 16 * (blockIdx.y + 16 * blockIdx.z);
  const int swz  = (orig & 7) * 128 + (orig >> 3);
  const int bn = (swz & 15) * 128;
  const int bm = ((swz >> 4) & 15) * 128;
  const int bt = swz >> 8;

  // staging base: thread t -> row (t>>3), permuted granule (t&7)^(row&7)
  const int srow_ = t >> 3;
  const int pg_   = (t & 7) ^ (srow_ & 7);
  const unsigned short* gA = qn + ((size_t)bt * S_LEN + bm + srow_) * D2_ + pg_ * 8;
  const unsigned short* gB = kb + ((size_t)bt * S_LEN + bn + srow_) * D2_ + pg_ * 8;
  unsigned short* lA = Asm_ + t * 8;
  unsigned short* lB = Bsm_ + t * 8;

  const int lane = t & 63;
  const int w  = t >> 6;
  const int wm = (w >> 2) * 64;   // wave m offset (0/64)
  const int wn = (w & 3) * 32;    // wave n offset (0/32/64/96)
  const int lr = lane & 15;
  const int lg = lane >> 4;

  // stage one 64-wide K-tile (32 KiB total) into the single buffer
  #define STAGE(koff) do {                                    \
      async16(gA + (koff),            lA);                    \
      async16(gA + (koff) + 64 * D2_, lA + 4096);             \
      async16(gB + (koff),            lB);                    \
      async16(gB + (koff) + 64 * D2_, lB + 4096);             \
    } while (0)

  f32x4 acc[4][2] = {};           // [fm][fn]

  STAGE(0);
  __syncthreads();   // tile 0 staged (drains vmcnt(0))

  // 16 K-tiles, serial 2-barrier loop; cross-block TLP (4 blocks/CU) fills
  // the drain bubbles.
  #pragma unroll 1
  for (int kt = 0; kt < 16; ++kt) {
    #pragma unroll
    for (int ks = 0; ks < 2; ++ks) {
      // K-chunk ks needs granule ks*4+lg: slot ((ks*4+lg) ^ (row&7)), row&7==lr&7
      const int sl = ((ks << 2) + lg) ^ (lr & 7);
      bf16x8 af[4], bfv[2];
      #pragma unroll
      for (int f = 0; f < 4; ++f)
        af[f]  = *(const bf16x8*)(Asm_ + (wm + f * 16 + lr) * 64 + sl * 8);
      #pragma unroll
      for (int f = 0; f < 2; ++f)
        bfv[f] = *(const bf16x8*)(Bsm_ + (wn + f * 16 + lr) * 64 + sl * 8);
      #pragma unroll
      for (int fm = 0; fm < 4; ++fm)
        #pragma unroll
        for (int fn = 0; fn < 2; ++fn)
          acc[fm][fn] = __builtin_amdgcn_mfma_f32_16x16x32_bf16(
              bfv[fn], af[fm], acc[fm][fn], 0, 0, 0);   // swapped order
    }
    __syncthreads();              // all reads of the buffer done
    if (kt < 15) {
      STAGE((kt + 1) * 64);
      __syncthreads();            // staged tile visible
    }
  }

  // epilogue: nontemporal mask loads (read-once 64 MB stream; don't pollute
  // L2) + masked stores + rowsum reduce.
  const int m_base = bm + wm + lr;
  const size_t rb0 = ((size_t)bt * S_LEN) * S_LEN;
  #pragma unroll
  for (int fm = 0; fm < 4; ++fm) {
    const int m = m_base + fm * 16;
    const size_t rowbase = rb0 + (size_t)m * S_LEN;
    float s = 0.f;
    #pragma unroll
    for (int fn = 0; fn < 2; ++fn) {
      const int n0 = bn + wn + fn * 16 + lg * 4;
      const i32x4 mk = __builtin_nontemporal_load((const i32x4*)(mask + rowbase + n0));
      f32x4 v;
      v[0] = mk[0] ? 0.0f : acc[fm][fn][0];
      v[1] = mk[1] ? 0.0f : acc[fm][fn][1];
      v[2] = mk[2] ? 0.0f : acc[fm][fn][2];
      v[3] = mk[3] ? 0.0f : acc[fm][fn][3];
      *(f32x4*)(attn + rowbase + n0) = v;
      s += v[0] + v[1] + v[2] + v[3];
    }
    // reduce across the 4 lg groups sharing this row
    s += __shfl_xor(s, 16);
    s += __shfl_xor(s, 32);
    if (lane < 16) atomicAdd(rowsum + (size_t)bt * S_LEN + m, s);
  }
  #undef STAGE
}

// ---------------------------------------------------------------------------
// Kernel 3: out[row,:] = rowsum[row] * w2[:] + fc_b[:] + q[row,:]
// (never touches attn).  Overwrites the out-region that held qn/kb; reads
// nothing from it — safe under stream ordering.
// ---------------------------------------------------------------------------
__global__ void __launch_bounds__(256) out_kernel(
    const float* __restrict__ rowsum, const float* __restrict__ q,
    const float* __restrict__ w2, const float* __restrict__ fcb,
    float* __restrict__ out) {
  const int row = blockIdx.x;
  const int t = threadIdx.x;
  const float rs = rowsum[row];
  const float4 wv = ((const float4*)w2)[t];
  const float4 bv = ((const float4*)fcb)[t];
  const float4 qv = ((const float4*)(q + (size_t)row * D2_))[t];
  float4 o4;
  o4.x = rs * wv.x + bv.x + qv.x;
  o4.y = rs * wv.y + bv.y + qv.y;
  o4.z = rs * wv.z + bv.z + qv.z;
  o4.w = rs * wv.w + bv.w + qv.w;
  ((float4*)(out + (size_t)row * D2_))[t] = o4;
}

// ---------------------------------------------------------------------------
extern "C" void kernel_launch(void* const* d_in, const int* in_sizes, int n_in,
                              void* d_out, int out_size, void* d_ws, size_t ws_size,
                              hipStream_t stream) {
  (void)in_sizes; (void)n_in; (void)out_size; (void)ws_size;
  const float* q    = (const float*)d_in[0];
  const float* k    = (const float*)d_in[1];
  /* d_in[2] == v: provably unused by the reference computation */
  const int*   mask = (const int*)d_in[3];
  const float* V    = (const float*)d_in[4];
  const float* fw   = (const float*)d_in[5];
  const float* fcb  = (const float*)d_in[6];
  const float* lg   = (const float*)d_in[7];
  const float* lb   = (const float*)d_in[8];

  float* out  = (float*)d_out;                          // [B,S,D2]  32 MiB
  float* attn = out + (size_t)NB_ * S_LEN * D2_;        // [B,S,S]   64 MiB

  // qn/kb live INSIDE the out-region (exactly 32 MiB), dead until out_kernel
  // overwrites it last.  d_ws: w2 (4 KiB) + rowsum (32 KiB).
  unsigned short* qn = (unsigned short*)out;                     // 16 MiB
  unsigned short* kb = qn + (size_t)NB_ * S_LEN * D2_;           // 16 MiB
  float* w2     = (float*)d_ws;                                  // 1024 f
  float* rowsum = w2 + D2_;                                      // 8192 f

  prep_kernel<<<NB_ * S_LEN, 256, 0, stream>>>(q, k, lg, lb, V, fw, qn, kb, w2, rowsum);
  attn_gemm_kernel<<<dim3(S_LEN / 128, S_LEN / 128, NB_), 512, 0, stream>>>(qn, kb, mask, attn, rowsum);
  out_kernel<<<NB_ * S_LEN, 256, 0, stream>>>(rowsum, q, w2, fcb, out);
}

// Round 5
// 265.462 us; speedup vs baseline: 1.0209x; 1.0165x over previous
//
#include <hip/hip_runtime.h>
#include <hip/hip_bf16.h>
#include <cstdint>

// Problem constants (B=4, S=2048, D2=1024, DV=64, d_k=64)
#define S_LEN 2048
#define D2_   1024
#define DV_   64
#define NB_   4

typedef __bf16 bf16x8 __attribute__((ext_vector_type(8)));
typedef float  f32x4  __attribute__((ext_vector_type(4)));
typedef int    i32x4  __attribute__((ext_vector_type(4)));

// fp32 -> bf16 round-to-nearest-even
__device__ __forceinline__ unsigned short f2bf(float f) {
  union { float f; unsigned int u; } v; v.f = f;
  unsigned int r = v.u + 0x7fffu + ((v.u >> 16) & 1u);
  return (unsigned short)(r >> 16);
}

// async global->LDS, 16B per lane (global_load_lds_dwordx4)
__device__ __forceinline__ void async16(const unsigned short* g, unsigned short* l) {
  __builtin_amdgcn_global_load_lds(
      (__attribute__((address_space(1))) void*)g,
      (__attribute__((address_space(3))) void*)l,
      16, 0, 0);
}

// ---------------------------------------------------------------------------
// Kernel 1 (fused prep): per row r:
//   qn[r,:] = bf16( LN(q[r,:]) * 0.125 )      (1/sqrt(64) folded in)
//   kb[r,:] = bf16( k[r,:] )
//   blocks 0..3:  w2[d] = fc_w[d,:] . V       (rank-1 collapse of @fc_w.T)
//   blocks 0..31: zero rowsum[] (d_ws is poisoned 0xAA before every launch)
// ---------------------------------------------------------------------------
__global__ void __launch_bounds__(256) prep_kernel(
    const float* __restrict__ q, const float* __restrict__ k,
    const float* __restrict__ gam, const float* __restrict__ bet,
    const float* __restrict__ V, const float* __restrict__ fw,
    unsigned short* __restrict__ qn, unsigned short* __restrict__ kb,
    float* __restrict__ w2, float* __restrict__ rowsum) {
  const int row = blockIdx.x;
  const int t = threadIdx.x;

  if (row < 32) rowsum[row * 256 + t] = 0.0f;   // 8192 floats total

  // ---- LN(q) ----
  const float4 x = ((const float4*)(q + (size_t)row * D2_))[t];
  float s  = x.x + x.y + x.z + x.w;
  float ss = x.x * x.x + x.y * x.y + x.z * x.z + x.w * x.w;
  #pragma unroll
  for (int o = 32; o > 0; o >>= 1) { s += __shfl_down(s, o); ss += __shfl_down(ss, o); }
  __shared__ float red[8];
  if ((t & 63) == 0) { red[t >> 6] = s; red[(t >> 6) + 4] = ss; }
  __syncthreads();
  const float tot  = red[0] + red[1] + red[2] + red[3];
  const float tots = red[4] + red[5] + red[6] + red[7];
  const float mu  = tot * (1.0f / D2_);
  const float var = tots * (1.0f / D2_) - mu * mu;
  const float rs  = rsqrtf(var + 1e-6f) * 0.125f;
  const float4 gv = ((const float4*)gam)[t];
  const float4 bv = ((const float4*)bet)[t];
  ushort4 o4;
  o4.x = f2bf((x.x - mu) * rs * gv.x + 0.125f * bv.x);
  o4.y = f2bf((x.y - mu) * rs * gv.y + 0.125f * bv.y);
  o4.z = f2bf((x.z - mu) * rs * gv.z + 0.125f * bv.z);
  o4.w = f2bf((x.w - mu) * rs * gv.w + 0.125f * bv.w);
  ((ushort4*)(qn + (size_t)row * D2_))[t] = o4;

  // ---- cast k row ----
  const float4 kx = ((const float4*)(k + (size_t)row * D2_))[t];
  ushort4 k4;
  k4.x = f2bf(kx.x); k4.y = f2bf(kx.y); k4.z = f2bf(kx.z); k4.w = f2bf(kx.w);
  ((ushort4*)(kb + (size_t)row * D2_))[t] = k4;

  // ---- w2 (blocks 0..3) ----
  if (row < 4) {
    const int d = row * 256 + t;
    const float4* r  = (const float4*)(fw + (size_t)d * DV_);
    const float4* vv = (const float4*)V;
    float acc = 0.f;
    #pragma unroll
    for (int j = 0; j < 16; ++j) {
      const float4 a = r[j], b = vv[j];
      acc += a.x * b.x + a.y * b.y + a.z * b.z + a.w * b.w;
    }
    w2[d] = acc;
  }
}

// ---------------------------------------------------------------------------
// Kernel 2: attn = masked( qn @ kb^T );  rowsum += per-row sums.
// R11: m97 wave shape.  R10 post-mortem: structure-bound (MfmaUtil 21% =
// exactly the 13.4us MFMA floor spread over 64us; HBM 27%; nothing
// saturated).  R10's 8-wave/64x32-per-wave split has MFMA:ds_read = 16:12
// per wave-tile; m97's proven 874-912 TF shape is 4 waves x 64x64
// (acc[4][4], 32 MFMA : 16 ds_read = 2:1, 2x per-wave ILP between
// barriers).  This kernel: 256 thr / 4 waves (2x2), same 128^2 tile, same
// BK=64 single buffer + 2-barrier serial loop, same granule-XOR LDS layout
// (row r at 128B stride, granule s at (s^(r&7))*16B; staging thread t ->
// row-quarter q*32+(t>>3), dest t*16B + q*4KiB, global granule
// (t&7)^(row&7)), same XCD-chunked swizzle (FETCH 106->69.6 MB proven),
// nt mask loads in epilogue.  __launch_bounds__(256,4) caps VGPR at 128
// (est ~115) -> 4 blocks/CU = 16 waves/CU, same TLP as R10 with double
// MFMA density.  MFMA operands swapped (kb first): m = wm+fm*16+(lane&15),
// n = wn+fn*16+(lane>>4)*4+j  (proven convention from R5-R10).
// ---------------------------------------------------------------------------
__global__ void __launch_bounds__(256, 4) attn_gemm_kernel(
    const unsigned short* __restrict__ qn,   // [B*S, D2] bf16
    const unsigned short* __restrict__ kb,   // [B*S, D2] bf16
    const int* __restrict__ mask,            // [B, S, S] int32
    float* __restrict__ attn,                // [B, S, S] f32
    float* __restrict__ rowsum) {            // [B*S] f32 (pre-zeroed)
  __shared__ __align__(16) unsigned short Asm_[8192];   // 16 KiB (single buf)
  __shared__ __align__(16) unsigned short Bsm_[8192];   // 16 KiB

  const int t = threadIdx.x;

  // XCD-chunked swizzle: XCD c owns contiguous work ids [c*128, (c+1)*128)
  // = 8 m-panels x all 16 n-panels (A panel reused 16x inside one L2).
  const int orig = blockIdx.x + 16 * (blockIdx.y + 16 * blockIdx.z);
  const int swz  = (orig & 7) * 128 + (orig >> 3);
  const int bn = (swz & 15) * 128;
  const int bm = ((swz >> 4) & 15) * 128;
  const int bt = swz >> 8;

  // staging base: thread t -> row (t>>3) of each 32-row quarter,
  // permuted granule (t&7)^(row&7)  (row&7 == (t>>3)&7 for all quarters)
  const int srow_ = t >> 3;                 // 0..31
  const int pg_   = (t & 7) ^ (srow_ & 7);
  const unsigned short* gA = qn + ((size_t)bt * S_LEN + bm + srow_) * D2_ + pg_ * 8;
  const unsigned short* gB = kb + ((size_t)bt * S_LEN + bn + srow_) * D2_ + pg_ * 8;
  unsigned short* lA = Asm_ + t * 8;
  unsigned short* lB = Bsm_ + t * 8;

  const int lane = t & 63;
  const int w  = t >> 6;                    // wave 0..3
  const int wm = (w >> 1) * 64;             // wave m offset (0/64)
  const int wn = (w & 1) * 64;              // wave n offset (0/64)
  const int lr = lane & 15;
  const int lg = lane >> 4;

  // stage one 64-wide K-tile (32 KiB total): 4 row-quarters per matrix
  #define STAGE(koff) do {                                          \
      _Pragma("unroll")                                             \
      for (int qq = 0; qq < 4; ++qq) {                              \
        async16(gA + (koff) + (size_t)qq * 32 * D2_, lA + qq * 2048); \
        async16(gB + (koff) + (size_t)qq * 32 * D2_, lB + qq * 2048); \
      }                                                             \
    } while (0)

  f32x4 acc[4][4] = {};           // [fm][fn]

  STAGE(0);
  __syncthreads();   // tile 0 staged (drains vmcnt(0))

  // 16 K-tiles, serial 2-barrier loop; cross-block TLP (4 blocks/CU) fills
  // the drain bubbles.
  #pragma unroll 1
  for (int kt = 0; kt < 16; ++kt) {
    #pragma unroll
    for (int ks = 0; ks < 2; ++ks) {
      // K-chunk ks needs granule ks*4+lg: slot ((ks*4+lg) ^ (row&7)), row&7==lr&7
      const int sl = ((ks << 2) + lg) ^ (lr & 7);
      bf16x8 af[4], bfv[4];
      #pragma unroll
      for (int f = 0; f < 4; ++f)
        af[f]  = *(const bf16x8*)(Asm_ + (wm + f * 16 + lr) * 64 + sl * 8);
      #pragma unroll
      for (int f = 0; f < 4; ++f)
        bfv[f] = *(const bf16x8*)(Bsm_ + (wn + f * 16 + lr) * 64 + sl * 8);
      #pragma unroll
      for (int fm = 0; fm < 4; ++fm)
        #pragma unroll
        for (int fn = 0; fn < 4; ++fn)
          acc[fm][fn] = __builtin_amdgcn_mfma_f32_16x16x32_bf16(
              bfv[fn], af[fm], acc[fm][fn], 0, 0, 0);   // swapped order
    }
    __syncthreads();              // all reads of the buffer done
    if (kt < 15) {
      STAGE((kt + 1) * 64);
      __syncthreads();            // staged tile visible
    }
  }

  // epilogue: nontemporal mask loads (read-once 64 MB stream; don't pollute
  // L2) + masked stores + rowsum reduce.
  const int m_base = bm + wm + lr;
  const size_t rb0 = ((size_t)bt * S_LEN) * S_LEN;
  #pragma unroll
  for (int fm = 0; fm < 4; ++fm) {
    const int m = m_base + fm * 16;
    const size_t rowbase = rb0 + (size_t)m * S_LEN;
    float s = 0.f;
    #pragma unroll
    for (int fn = 0; fn < 4; ++fn) {
      const int n0 = bn + wn + fn * 16 + lg * 4;
      const i32x4 mk = __builtin_nontemporal_load((const i32x4*)(mask + rowbase + n0));
      f32x4 v;
      v[0] = mk[0] ? 0.0f : acc[fm][fn][0];
      v[1] = mk[1] ? 0.0f : acc[fm][fn][1];
      v[2] = mk[2] ? 0.0f : acc[fm][fn][2];
      v[3] = mk[3] ? 0.0f : acc[fm][fn][3];
      *(f32x4*)(attn + rowbase + n0) = v;
      s += v[0] + v[1] + v[2] + v[3];
    }
    // reduce across the 4 lg groups sharing this row
    s += __shfl_xor(s, 16);
    s += __shfl_xor(s, 32);
    if (lane < 16) atomicAdd(rowsum + (size_t)bt * S_LEN + m, s);
  }
  #undef STAGE
}

// ---------------------------------------------------------------------------
// Kernel 3: out[row,:] = rowsum[row] * w2[:] + fc_b[:] + q[row,:]
// (never touches attn).  Overwrites the out-region that held qn/kb; reads
// nothing from it — safe under stream ordering.
// ---------------------------------------------------------------------------
__global__ void __launch_bounds__(256) out_kernel(
    const float* __restrict__ rowsum, const float* __restrict__ q,
    const float* __restrict__ w2, const float* __restrict__ fcb,
    float* __restrict__ out) {
  const int row = blockIdx.x;
  const int t = threadIdx.x;
  const float rs = rowsum[row];
  const float4 wv = ((const float4*)w2)[t];
  const float4 bv = ((const float4*)fcb)[t];
  const float4 qv = ((const float4*)(q + (size_t)row * D2_))[t];
  float4 o4;
  o4.x = rs * wv.x + bv.x + qv.x;
  o4.y = rs * wv.y + bv.y + qv.y;
  o4.z = rs * wv.z + bv.z + qv.z;
  o4.w = rs * wv.w + bv.w + qv.w;
  ((float4*)(out + (size_t)row * D2_))[t] = o4;
}

// ---------------------------------------------------------------------------
extern "C" void kernel_launch(void* const* d_in, const int* in_sizes, int n_in,
                              void* d_out, int out_size, void* d_ws, size_t ws_size,
                              hipStream_t stream) {
  (void)in_sizes; (void)n_in; (void)out_size; (void)ws_size;
  const float* q    = (const float*)d_in[0];
  const float* k    = (const float*)d_in[1];
  /* d_in[2] == v: provably unused by the reference computation */
  const int*   mask = (const int*)d_in[3];
  const float* V    = (const float*)d_in[4];
  const float* fw   = (const float*)d_in[5];
  const float* fcb  = (const float*)d_in[6];
  const float* lg   = (const float*)d_in[7];
  const float* lb   = (const float*)d_in[8];

  float* out  = (float*)d_out;                          // [B,S,D2]  32 MiB
  float* attn = out + (size_t)NB_ * S_LEN * D2_;        // [B,S,S]   64 MiB

  // qn/kb live INSIDE the out-region (exactly 32 MiB), dead until out_kernel
  // overwrites it last.  d_ws: w2 (4 KiB) + rowsum (32 KiB).
  unsigned short* qn = (unsigned short*)out;                     // 16 MiB
  unsigned short* kb = qn + (size_t)NB_ * S_LEN * D2_;           // 16 MiB
  float* w2     = (float*)d_ws;                                  // 1024 f
  float* rowsum = w2 + D2_;                                      // 8192 f

  prep_kernel<<<NB_ * S_LEN, 256, 0, stream>>>(q, k, lg, lb, V, fw, qn, kb, w2, rowsum);
  attn_gemm_kernel<<<dim3(S_LEN / 128, S_LEN / 128, NB_), 256, 0, stream>>>(qn, kb, mask, attn, rowsum);
  out_kernel<<<NB_ * S_LEN, 256, 0, stream>>>(rowsum, q, w2, fcb, out);
}

// Round 6
// 265.073 us; speedup vs baseline: 1.0224x; 1.0015x over previous
//
#include <hip/hip_runtime.h>
#include <hip/hip_bf16.h>
#include <cstdint>

// Problem constants (B=4, S=2048, D2=1024, DV=64, d_k=64)
#define S_LEN 2048
#define D2_   1024
#define DV_   64
#define NB_   4

typedef __bf16 bf16x8 __attribute__((ext_vector_type(8)));
typedef float  f32x4  __attribute__((ext_vector_type(4)));
typedef int    i32x4  __attribute__((ext_vector_type(4)));

// fp32 -> bf16 round-to-nearest-even
__device__ __forceinline__ unsigned short f2bf(float f) {
  union { float f; unsigned int u; } v; v.f = f;
  unsigned int r = v.u + 0x7fffu + ((v.u >> 16) & 1u);
  return (unsigned short)(r >> 16);
}

// async global->LDS, 16B per lane (global_load_lds_dwordx4)
__device__ __forceinline__ void async16(const unsigned short* g, unsigned short* l) {
  __builtin_amdgcn_global_load_lds(
      (__attribute__((address_space(1))) void*)g,
      (__attribute__((address_space(3))) void*)l,
      16, 0, 0);
}

// ---------------------------------------------------------------------------
// Kernel 1 (fused prep): per row r:
//   qn[r,:] = bf16( LN(q[r,:]) * 0.125 )      (1/sqrt(64) folded in)
//   kb[r,:] = bf16( k[r,:] )
//   blocks 0..3:  w2[d] = fc_w[d,:] . V       (rank-1 collapse of @fc_w.T)
//   blocks 0..31: zero rowsum[] (d_ws is poisoned 0xAA before every launch)
// ---------------------------------------------------------------------------
__global__ void __launch_bounds__(256) prep_kernel(
    const float* __restrict__ q, const float* __restrict__ k,
    const float* __restrict__ gam, const float* __restrict__ bet,
    const float* __restrict__ V, const float* __restrict__ fw,
    unsigned short* __restrict__ qn, unsigned short* __restrict__ kb,
    float* __restrict__ w2, float* __restrict__ rowsum) {
  const int row = blockIdx.x;
  const int t = threadIdx.x;

  if (row < 32) rowsum[row * 256 + t] = 0.0f;   // 8192 floats total

  // ---- LN(q) ----
  const float4 x = ((const float4*)(q + (size_t)row * D2_))[t];
  float s  = x.x + x.y + x.z + x.w;
  float ss = x.x * x.x + x.y * x.y + x.z * x.z + x.w * x.w;
  #pragma unroll
  for (int o = 32; o > 0; o >>= 1) { s += __shfl_down(s, o); ss += __shfl_down(ss, o); }
  __shared__ float red[8];
  if ((t & 63) == 0) { red[t >> 6] = s; red[(t >> 6) + 4] = ss; }
  __syncthreads();
  const float tot  = red[0] + red[1] + red[2] + red[3];
  const float tots = red[4] + red[5] + red[6] + red[7];
  const float mu  = tot * (1.0f / D2_);
  const float var = tots * (1.0f / D2_) - mu * mu;
  const float rs  = rsqrtf(var + 1e-6f) * 0.125f;
  const float4 gv = ((const float4*)gam)[t];
  const float4 bv = ((const float4*)bet)[t];
  ushort4 o4;
  o4.x = f2bf((x.x - mu) * rs * gv.x + 0.125f * bv.x);
  o4.y = f2bf((x.y - mu) * rs * gv.y + 0.125f * bv.y);
  o4.z = f2bf((x.z - mu) * rs * gv.z + 0.125f * bv.z);
  o4.w = f2bf((x.w - mu) * rs * gv.w + 0.125f * bv.w);
  ((ushort4*)(qn + (size_t)row * D2_))[t] = o4;

  // ---- cast k row ----
  const float4 kx = ((const float4*)(k + (size_t)row * D2_))[t];
  ushort4 k4;
  k4.x = f2bf(kx.x); k4.y = f2bf(kx.y); k4.z = f2bf(kx.z); k4.w = f2bf(kx.w);
  ((ushort4*)(kb + (size_t)row * D2_))[t] = k4;

  // ---- w2 (blocks 0..3) ----
  if (row < 4) {
    const int d = row * 256 + t;
    const float4* r  = (const float4*)(fw + (size_t)d * DV_);
    const float4* vv = (const float4*)V;
    float acc = 0.f;
    #pragma unroll
    for (int j = 0; j < 16; ++j) {
      const float4 a = r[j], b = vv[j];
      acc += a.x * b.x + a.y * b.y + a.z * b.z + a.w * b.w;
    }
    w2[d] = acc;
  }
}

// ---------------------------------------------------------------------------
// Kernel 2: attn = masked( qn @ kb^T );  rowsum += per-row sums.
// R12: mask-into-K-loop.  R11 decomposition: K-loop ~42us (structure-bound,
// HBM-idle: panels are L2-resident, FETCH-mask = 64 of 67 MB) + epilogue
// burst ~20us (mask 64MB read + attn 64MB write, BW-bound, serial tail
// since all blocks are phase-synchronized).  Fix: load the mask DURING the
// K-loop (BW-idle window) and compress each thread's 16 mask words to 16
// BITS (two u32s, 2 VGPRs) -- fm-group g's 4 nt-int4 loads + nibble-pack
// happen at the top of K-iteration g (g=0..3).  Epilogue becomes pure
// stores.  Everything else identical to R11: m97 wave shape (4 waves,
// 64x64/wave, acc[4][4]), 128^2 tile, BK=64 single 32KiB buffer, 2-barrier
// serial loop, granule-XOR LDS layout (row r at 128B stride, granule s at
// (s^(r&7))*16B), XCD-chunked bijective swizzle (FETCH 106->67 MB proven),
// swapped MFMA operands (kb first): m = wm+fm*16+(lane&15),
// n = wn+fn*16+(lane>>4)*4+j.
// ---------------------------------------------------------------------------
__global__ void __launch_bounds__(256, 4) attn_gemm_kernel(
    const unsigned short* __restrict__ qn,   // [B*S, D2] bf16
    const unsigned short* __restrict__ kb,   // [B*S, D2] bf16
    const int* __restrict__ mask,            // [B, S, S] int32
    float* __restrict__ attn,                // [B, S, S] f32
    float* __restrict__ rowsum) {            // [B*S] f32 (pre-zeroed)
  __shared__ __align__(16) unsigned short Asm_[8192];   // 16 KiB (single buf)
  __shared__ __align__(16) unsigned short Bsm_[8192];   // 16 KiB

  const int t = threadIdx.x;

  // XCD-chunked swizzle: XCD c owns contiguous work ids [c*128, (c+1)*128)
  // = 8 m-panels x all 16 n-panels (A panel reused 16x inside one L2).
  const int orig = blockIdx.x + 16 * (blockIdx.y + 16 * blockIdx.z);
  const int swz  = (orig & 7) * 128 + (orig >> 3);
  const int bn = (swz & 15) * 128;
  const int bm = ((swz >> 4) & 15) * 128;
  const int bt = swz >> 8;

  // staging base: thread t -> row (t>>3) of each 32-row quarter,
  // permuted granule (t&7)^(row&7)  (row&7 == (t>>3)&7 for all quarters)
  const int srow_ = t >> 3;                 // 0..31
  const int pg_   = (t & 7) ^ (srow_ & 7);
  const unsigned short* gA = qn + ((size_t)bt * S_LEN + bm + srow_) * D2_ + pg_ * 8;
  const unsigned short* gB = kb + ((size_t)bt * S_LEN + bn + srow_) * D2_ + pg_ * 8;
  unsigned short* lA = Asm_ + t * 8;
  unsigned short* lB = Bsm_ + t * 8;

  const int lane = t & 63;
  const int w  = t >> 6;                    // wave 0..3
  const int wm = (w >> 1) * 64;             // wave m offset (0/64)
  const int wn = (w & 1) * 64;              // wave n offset (0/64)
  const int lr = lane & 15;
  const int lg = lane >> 4;

  // mask geometry (used inside the K-loop for the compressed prefetch)
  const int m_base = bm + wm + lr;
  const size_t rb0 = ((size_t)bt * S_LEN) * S_LEN;
  const int n_base = bn + wn + lg * 4;

  // stage one 64-wide K-tile (32 KiB total): 4 row-quarters per matrix
  #define STAGE(koff) do {                                          \
      _Pragma("unroll")                                             \
      for (int qq = 0; qq < 4; ++qq) {                              \
        async16(gA + (koff) + (size_t)qq * 32 * D2_, lA + qq * 2048); \
        async16(gB + (koff) + (size_t)qq * 32 * D2_, lB + qq * 2048); \
      }                                                             \
    } while (0)

  f32x4 acc[4][4] = {};           // [fm][fn]
  unsigned int mklo = 0, mkhi = 0;   // 16 nibbles: bit (fm*16+fn*4+j), fm split lo/hi

  STAGE(0);
  __syncthreads();   // tile 0 staged (drains vmcnt(0))

  // 16 K-tiles, serial 2-barrier loop; cross-block TLP (4 blocks/CU) fills
  // the drain bubbles.  Iterations 0..3 additionally stream one fm-group of
  // the mask (4 nt int4 loads -> one nibble each) into mklo/mkhi -- the
  // 64 MB mask read rides the BW-idle K-loop window instead of the tail.
  #pragma unroll 1
  for (int kt = 0; kt < 16; ++kt) {
    if (kt < 4) {
      const int fm = kt;
      const size_t mrow = rb0 + (size_t)(m_base + fm * 16) * S_LEN + n_base;
      unsigned int nib4 = 0;
      #pragma unroll
      for (int fn = 0; fn < 4; ++fn) {
        const i32x4 mm = __builtin_nontemporal_load((const i32x4*)(mask + mrow + fn * 16));
        const unsigned int nib = (mm[0] ? 1u : 0u) | (mm[1] ? 2u : 0u) |
                                 (mm[2] ? 4u : 0u) | (mm[3] ? 8u : 0u);
        nib4 |= nib << (fn * 4);
      }
      if (fm < 2) mklo |= nib4 << (fm * 16);
      else        mkhi |= nib4 << ((fm - 2) * 16);
    }
    #pragma unroll
    for (int ks = 0; ks < 2; ++ks) {
      // K-chunk ks needs granule ks*4+lg: slot ((ks*4+lg) ^ (row&7)), row&7==lr&7
      const int sl = ((ks << 2) + lg) ^ (lr & 7);
      bf16x8 af[4], bfv[4];
      #pragma unroll
      for (int f = 0; f < 4; ++f)
        af[f]  = *(const bf16x8*)(Asm_ + (wm + f * 16 + lr) * 64 + sl * 8);
      #pragma unroll
      for (int f = 0; f < 4; ++f)
        bfv[f] = *(const bf16x8*)(Bsm_ + (wn + f * 16 + lr) * 64 + sl * 8);
      #pragma unroll
      for (int fm = 0; fm < 4; ++fm)
        #pragma unroll
        for (int fn = 0; fn < 4; ++fn)
          acc[fm][fn] = __builtin_amdgcn_mfma_f32_16x16x32_bf16(
              bfv[fn], af[fm], acc[fm][fn], 0, 0, 0);   // swapped order
    }
    __syncthreads();              // all reads of the buffer done
    if (kt < 15) {
      STAGE((kt + 1) * 64);
      __syncthreads();            // staged tile visible
    }
  }

  // epilogue: pure stores (mask already compressed in 2 regs) + rowsum.
  #pragma unroll
  for (int fm = 0; fm < 4; ++fm) {
    const int m = m_base + fm * 16;
    const size_t rowbase = rb0 + (size_t)m * S_LEN;
    const unsigned int bits16 = (fm < 2 ? mklo : mkhi) >> ((fm & 1) * 16);
    float s = 0.f;
    #pragma unroll
    for (int fn = 0; fn < 4; ++fn) {
      const int n0 = bn + wn + fn * 16 + lg * 4;
      const unsigned int nib = (bits16 >> (fn * 4)) & 0xFu;
      f32x4 v;
      v[0] = (nib & 1u) ? 0.0f : acc[fm][fn][0];
      v[1] = (nib & 2u) ? 0.0f : acc[fm][fn][1];
      v[2] = (nib & 4u) ? 0.0f : acc[fm][fn][2];
      v[3] = (nib & 8u) ? 0.0f : acc[fm][fn][3];
      *(f32x4*)(attn + rowbase + n0) = v;
      s += v[0] + v[1] + v[2] + v[3];
    }
    // reduce across the 4 lg groups sharing this row
    s += __shfl_xor(s, 16);
    s += __shfl_xor(s, 32);
    if (lane < 16) atomicAdd(rowsum + (size_t)bt * S_LEN + m, s);
  }
  #undef STAGE
}

// ---------------------------------------------------------------------------
// Kernel 3: out[row,:] = rowsum[row] * w2[:] + fc_b[:] + q[row,:]
// (never touches attn).  Overwrites the out-region that held qn/kb; reads
// nothing from it — safe under stream ordering.
// ---------------------------------------------------------------------------
__global__ void __launch_bounds__(256) out_kernel(
    const float* __restrict__ rowsum, const float* __restrict__ q,
    const float* __restrict__ w2, const float* __restrict__ fcb,
    float* __restrict__ out) {
  const int row = blockIdx.x;
  const int t = threadIdx.x;
  const float rs = rowsum[row];
  const float4 wv = ((const float4*)w2)[t];
  const float4 bv = ((const float4*)fcb)[t];
  const float4 qv = ((const float4*)(q + (size_t)row * D2_))[t];
  float4 o4;
  o4.x = rs * wv.x + bv.x + qv.x;
  o4.y = rs * wv.y + bv.y + qv.y;
  o4.z = rs * wv.z + bv.z + qv.z;
  o4.w = rs * wv.w + bv.w + qv.w;
  ((float4*)(out + (size_t)row * D2_))[t] = o4;
}

// ---------------------------------------------------------------------------
extern "C" void kernel_launch(void* const* d_in, const int* in_sizes, int n_in,
                              void* d_out, int out_size, void* d_ws, size_t ws_size,
                              hipStream_t stream) {
  (void)in_sizes; (void)n_in; (void)out_size; (void)ws_size;
  const float* q    = (const float*)d_in[0];
  const float* k    = (const float*)d_in[1];
  /* d_in[2] == v: provably unused by the reference computation */
  const int*   mask = (const int*)d_in[3];
  const float* V    = (const float*)d_in[4];
  const float* fw   = (const float*)d_in[5];
  const float* fcb  = (const float*)d_in[6];
  const float* lg   = (const float*)d_in[7];
  const float* lb   = (const float*)d_in[8];

  float* out  = (float*)d_out;                          // [B,S,D2]  32 MiB
  float* attn = out + (size_t)NB_ * S_LEN * D2_;        // [B,S,S]   64 MiB

  // qn/kb live INSIDE the out-region (exactly 32 MiB), dead until out_kernel
  // overwrites it last.  d_ws: w2 (4 KiB) + rowsum (32 KiB).
  unsigned short* qn = (unsigned short*)out;                     // 16 MiB
  unsigned short* kb = qn + (size_t)NB_ * S_LEN * D2_;           // 16 MiB
  float* w2     = (float*)d_ws;                                  // 1024 f
  float* rowsum = w2 + D2_;                                      // 8192 f

  prep_kernel<<<NB_ * S_LEN, 256, 0, stream>>>(q, k, lg, lb, V, fw, qn, kb, w2, rowsum);
  attn_gemm_kernel<<<dim3(S_LEN / 128, S_LEN / 128, NB_), 256, 0, stream>>>(qn, kb, mask, attn, rowsum);
  out_kernel<<<NB_ * S_LEN, 256, 0, stream>>>(rowsum, q, w2, fcb, out);
}